// Round 20
// baseline (146.609 us; speedup 1.0000x reference)
//
#include <hip/hip_runtime.h>
#include <stdint.h>

// Match numpy's unfused mul/add rounding everywhere (no FMA contraction).
#pragma clang fp contract(off)

typedef unsigned long long ull;

// Problem constants (B=16, H=W=64, A=9, stride 16, img 1024x1024)
#define NB 16
#define NA 9
#define HW 4096
#define NANCH (NA*HW)         // 36864
#define TOTAL (NB*NANCH)      // 589824
#define TOPN 2000
#define PADN 2048             // box/area buffer stride
#define SELPAD 3072           // candidate buffer per batch
#define OUTN 300
#define HBITS 13
#define HBINS (1 << HBITS)    // 8192 LDS histogram bins
#define MROWS 2048            // mask row stride (rows 0..1999 used)
#define MW 32                 // ull words per mask row (2048 bits)
#define GDS 16                // scan prefetch depth

// exact: RN32(inter/u) > 0.7f  <=>  (double)inter >= MIDC*(double)u
// (HW-verified: absmax 0 in rounds 9-19.)
#define MIDC 0x1.666667p-1

// 9 base anchors (x1,y1,x2,y2), computed exactly per the numpy generator
__constant__ float c_ax1[9] = {-3.5f,-15.f,-38.f,  0.f, -8.f,-24.f,  2.5f, -3.f,-14.f};
__constant__ float c_ay1[9] = { 2.f,  -4.f,-16.f,  0.f, -8.f,-24.f, -3.f,-14.f,-36.f};
__constant__ float c_ax2[9] = {18.5f, 30.f, 53.f, 15.f, 23.f, 39.f, 12.5f, 18.f, 29.f};
__constant__ float c_ay2[9] = {13.f,  19.f, 31.f, 15.f, 23.f, 39.f, 18.f,  29.f, 51.f};

__device__ __forceinline__ void decode_box(int a, int x, int y,
    float d0, float d1, float d2, float d3,
    float& x1, float& y1, float& x2, float& y2) {
  float ax1 = c_ax1[a] + 16.f * (float)x;
  float ay1 = c_ay1[a] + 16.f * (float)y;
  float ax2 = c_ax2[a] + 16.f * (float)x;
  float ay2 = c_ay2[a] + 16.f * (float)y;
  float aw  = ax2 - ax1 + 1.f;
  float ah  = ay2 - ay1 + 1.f;
  float acx = ax1 + 0.5f * aw;
  float acy = ay1 + 0.5f * ah;
  float cx = d0 * aw + acx;
  float cy = d1 * ah + acy;
  float pw = expf(d2) * aw;
  float ph = expf(d3) * ah;
  x1 = cx - 0.5f * pw;
  y1 = cy - 0.5f * ph;
  x2 = cx + 0.5f * pw;
  y2 = cy + 0.5f * ph;
  x1 = fminf(fmaxf(x1, 0.f), 1023.f);
  y1 = fminf(fmaxf(y1, 0.f), 1023.f);
  x2 = fminf(fmaxf(x2, 0.f), 1023.f);
  y2 = fminf(fmaxf(y2, 0.f), 1023.f);
}

__device__ __forceinline__ uint32_t f2ord(float f) {
  uint32_t u = __float_as_uint(f);
  return (u & 0x80000000u) ? ~u : (u | 0x80000000u);
}
__device__ __forceinline__ float ord2f(uint32_t u) {
  return (u & 0x80000000u) ? __uint_as_float(u ^ 0x80000000u) : __uint_as_float(~u);
}

// Kernel 1: masked ordered score keys, coalesced linear write keys[t].
// (r15-proven scalar form.)
__global__ void k_score(const float* __restrict__ labels, const float* __restrict__ bbox,
                        uint32_t* __restrict__ keys) {
  int t = blockIdx.x * 256 + threadIdx.x;
  if (t >= TOTAL) return;
  int pos = t & (HW - 1);
  int ba  = t >> 12;
  int a = ba % 9, b = ba / 9;
  float score = labels[((b * 18 + 2 * a + 1) << 12) + pos];
  const float* dp = bbox + ((b * 36 + 4 * a) << 12) + pos;
  float d0 = dp[0], d1 = dp[4096], d2 = dp[8192], d3 = dp[12288];
  int y = pos >> 6, x = pos & 63;
  float x1, y1, x2, y2;
  decode_box(a, x, y, d0, d1, d2, d3, x1, y1, x2, y2);
  bool keep = (x2 - x1 + 1.f >= 16.f) && (y2 - y1 + 1.f >= 16.f);
  float s = keep ? score : -INFINITY;
  keys[t] = f2ord(s);
}

// Kernel 2: per-batch LDS histogram + suffix scan for top-2000 threshold bin
// + compaction. 16 blocks x 1024. Proven round 15.
__global__ __launch_bounds__(1024) void k_batch(const uint32_t* __restrict__ keys,
                                                ull* __restrict__ selKeys,
                                                uint32_t* __restrict__ counters) {
  int b = blockIdx.x, tid = threadIdx.x;
  int wave = tid >> 6, lane = tid & 63;
  __shared__ uint32_t hist[HBINS];         // 32 KB
  __shared__ uint32_t wtot[16];
  __shared__ uint32_t sh_T, sh_cnt;
  const uint32_t* kb = keys + b * NANCH;
  const uint4* kb4 = (const uint4*)kb;
#pragma unroll
  for (int k = 0; k < HBINS / 1024; ++k) hist[k * 1024 + tid] = 0u;
  if (tid == 0) { sh_T = 0u; sh_cnt = 0u; }
  __syncthreads();
  for (int i4 = tid; i4 < NANCH / 4; i4 += 1024) {
    uint4 v = kb4[i4];
    if (v.x & 0x80000000u) atomicAdd(&hist[v.x >> (32 - HBITS)], 1u);
    if (v.y & 0x80000000u) atomicAdd(&hist[v.y >> (32 - HBITS)], 1u);
    if (v.z & 0x80000000u) atomicAdd(&hist[v.z >> (32 - HBITS)], 1u);
    if (v.w & 0x80000000u) atomicAdd(&hist[v.w >> (32 - HBITS)], 1u);
  }
  __syncthreads();
  uint32_t c[8], suf[8];
#pragma unroll
  for (int k = 0; k < 8; ++k) c[k] = hist[tid * 8 + k];
  suf[7] = c[7];
#pragma unroll
  for (int k = 6; k >= 0; --k) suf[k] = c[k] + suf[k + 1];
  uint32_t total = suf[0];
  uint32_t wsuf = total;
#pragma unroll
  for (int off = 1; off < 64; off <<= 1) {
    uint32_t v = __shfl_down(wsuf, off);
    if (lane + off < 64) wsuf += v;
  }
  if (lane == 0) wtot[wave] = wsuf;
  __syncthreads();
  uint32_t wab = 0;
  for (int w = wave + 1; w < 16; ++w) wab += wtot[w];
  uint32_t ssum = wsuf + wab;          // keys in bins >= 8*tid
  uint32_t above_t = ssum - total;     // keys in bins >= 8*(tid+1)
  if (above_t < TOPN && ssum >= TOPN) {
    uint32_t T = (uint32_t)(tid * 8);
#pragma unroll
    for (int k = 7; k >= 0; --k) {
      uint32_t ab = above_t + ((k < 7) ? suf[k + 1] : 0u);
      if (ab < TOPN && ab + c[k] >= TOPN) T = (uint32_t)(tid * 8 + k);
    }
    sh_T = T;
  }
  __syncthreads();
  uint32_t T = sh_T;
  for (int i4 = tid; i4 < NANCH / 4; i4 += 1024) {
    uint4 v = kb4[i4];
    uint32_t vv[4] = { v.x, v.y, v.z, v.w };
#pragma unroll
    for (int cc = 0; cc < 4; ++cc) {
      uint32_t u = vv[cc];
      if ((u >> (32 - HBITS)) >= T) {
        uint32_t slot = atomicAdd(&sh_cnt, 1u);
        if (slot < SELPAD) {
          int i = i4 * 4 + cc;
          uint32_t canon = (uint32_t)((i & 4095) * 9 + (i >> 12));  // pos*9 + a
          selKeys[b * SELPAD + slot] = (((ull)(~u)) << 32) | canon;
        }
      }
    }
  }
  __syncthreads();
  if (tid == 0) counters[b] = (sh_cnt < SELPAD) ? sh_cnt : SELPAD;
}

// Kernel 3: rank-by-counting + decode + scatter. Proven round 15.
// (count(>=T) >= 2000 always, so ranks 0..1999 are all written.)
__global__ __launch_bounds__(256) void k_rank(const ull* __restrict__ selKeys,
                        const uint32_t* __restrict__ counters, const float* __restrict__ bbox,
                        float4* __restrict__ boxes, float* __restrict__ areas,
                        float* __restrict__ selScore) {
  int b = blockIdx.y;
  int i = blockIdx.x * 256 + threadIdx.x;
  int tid = threadIdx.x;
  uint32_t n = counters[b];
  const ull* sk = selKeys + b * SELPAD;
  ull ki = (i < (int)n) ? sk[i] : ~0ull;
  int rank = 0;
  __shared__ ull chunk[256];
  for (uint32_t base = 0; base < n; base += 256) {
    uint32_t j = base + (uint32_t)tid;
    chunk[tid] = (j < n) ? sk[j] : ~0ull;
    __syncthreads();
    int lim = (int)(n - base < 256u ? n - base : 256u);
    for (int t2 = 0; t2 < lim; ++t2) rank += (chunk[t2] < ki) ? 1 : 0;
    __syncthreads();
  }
  if (i < (int)n && rank < TOPN) {
    uint32_t idx = (uint32_t)ki;
    selScore[b * TOPN + rank] = ord2f(~((uint32_t)(ki >> 32)));
    int pos = (int)idx / 9, a = (int)idx - 9 * pos;
    int y = pos >> 6, x = pos & 63;
    const float* dp = bbox + ((b * 36 + 4 * a) << 12) + pos;
    float d0 = dp[0], d1 = dp[4096], d2 = dp[8192], d3 = dp[12288];
    float x1, y1, x2, y2;
    decode_box(a, x, y, d0, d1, d2, d3, x1, y1, x2, y2);
    boxes[b * PADN + rank] = make_float4(x1, y1, x2, y2);
    areas[b * PADN + rank] = (x2 - x1 + 1.f) * (y2 - y1 + 1.f);
  }
}

// Kernel 4: FULL suppression mask (all 2000 candidates). Grid (63, 16) x 256.
// Block owns 32 consecutive rows (shares smin = rbase>>6); strips s in
// [smin, 32) looped with the column box reloaded per strip (no VGPR blowup).
// j >= TOPN guarded in the ballot predicate; rows >= TOPN not stored.
__global__ __launch_bounds__(256) void k_mask(const float4* __restrict__ boxes,
                                              const float* __restrict__ areas,
                                              ull* __restrict__ gmask) {
  int rb = blockIdx.x, b = blockIdx.y;
  int tid = threadIdx.x, wv = tid >> 6, lane = tid & 63;
  int rbase = rb * 32;
  int smin = rbase >> 6;
  __shared__ float4 sRow[32];
  __shared__ float  sAr[32];
  if (tid < 32) {
    sRow[tid] = boxes[b * PADN + rbase + tid];
    sAr[tid]  = areas[b * PADN + rbase + tid];
  }
  __syncthreads();
  const double MD = MIDC;
  for (int s = smin; s < 32; ++s) {
    int j = (s << 6) + lane;
    float4 bj = boxes[b * PADN + j];      // j <= 2047, in-bounds
    float  ja = areas[b * PADN + j];
    bool jvalid = (j < TOPN);
    for (int r = wv; r < 32; r += 4) {
      int i = rbase + r;
      float4 bi = sRow[r];
      float  ia = sAr[r];
      float iw = fminf(bi.z, bj.z) - fmaxf(bi.x, bj.x) + 1.f; iw = fmaxf(iw, 0.f);
      float ih = fminf(bi.w, bj.w) - fmaxf(bi.y, bj.y) + 1.f; ih = fmaxf(ih, 0.f);
      float inter = iw * ih;
      float uu = (ia + ja) - inter;
      bool sup = jvalid && (j > i) && ((double)inter >= MD * (double)uu);
      ull mb = __ballot(sup);
      if (lane == 0 && i < TOPN) gmask[((size_t)b * MROWS + i) * MW + s] = mb;
    }
  }
}

// Kernel 5: single-wave greedy scan over the FULL mask (r2/r9-proven loop):
// lane owns u32 word `lane` of the 2048-bit suppression bitmap; GDS-deep
// register prefetch from global; shfl bit test; below-diagonal (unwritten)
// u32 words masked to 0; exact early exit at 300 kept. NO fallback — the
// mask covers all 2000 candidates.
__global__ __launch_bounds__(64) void k_scan(const ull* __restrict__ gmask,
                                             const float4* __restrict__ boxes,
                                             const float* __restrict__ selScore,
                                             float* __restrict__ out) {
  int b = blockIdx.x, lane = threadIdx.x;   // 64 threads = 1 wave
  const uint32_t* mrows = (const uint32_t*)(gmask + (size_t)b * MROWS * MW);
  __shared__ int kidx[OUTN];
  __shared__ int sh_cnt;
  uint32_t m[GDS];
#pragma unroll
  for (int ph = 0; ph < GDS; ++ph) m[ph] = mrows[ph * 64 + lane];
  uint32_t supw = 0u;                 // lane l owns u32 word l
  int cnt = 0;
  for (int base = 0; base < TOPN && cnt < OUTN; base += GDS) {
#pragma unroll
    for (int ph = 0; ph < GDS; ++ph) {
      int i = base + ph;
      uint32_t sw = __shfl(supw, i >> 5);          // word holding bit i
      if (!((sw >> (i & 31)) & 1u)) {              // uniform
        // u32 words < 2*(i>>6) are below-diagonal (unwritten) -> 0
        uint32_t mm = (lane >= (uint32_t)((i >> 6) << 1)) ? m[ph] : 0u;
        supw |= mm;
        if (lane == 0 && cnt < OUTN) kidx[cnt] = i;
        cnt++;
      }
      int nx = i + GDS; if (nx > TOPN - 1) nx = TOPN - 1;
      m[ph] = mrows[nx * 64 + lane];               // prefetch
    }
  }
  if (lane == 0) sh_cnt = (cnt < OUTN) ? cnt : OUTN;
  __syncthreads();
  int c = sh_cnt;
  float4* ob = (float4*)out;
  for (int s2 = lane; s2 < OUTN; s2 += 64) {
    float4 bx = make_float4(0.f, 0.f, 0.f, 0.f);
    float sc = 0.f;
    if (s2 < c) {
      int i = kidx[s2];
      bx = boxes[b * PADN + i];
      sc = selScore[b * TOPN + i];
    }
    ob[b * OUTN + s2] = bx;
    out[NB * OUTN * 4 + b * OUTN + s2] = sc;
  }
}

extern "C" void kernel_launch(void* const* d_in, const int* in_sizes, int n_in,
                              void* d_out, int out_size, void* d_ws, size_t ws_size,
                              hipStream_t stream) {
  const float* labels = (const float*)d_in[0];  // (16, 18, 64, 64)
  const float* bbox   = (const float*)d_in[1];  // (16, 36, 64, 64)
  char* ws = (char*)d_ws;
  // workspace layout (bytes):
  uint32_t* keys    = (uint32_t*)(ws + 0);         // 589824*4      = 2,359,296
  ull* selKeys      = (ull*)(ws + 2359296);        // 16*3072*8     =   393,216
  float* selScore   = (float*)(ws + 2752512);      // 16*2000*4     =   128,000
  float* areas      = (float*)(ws + 2880512);      // 16*2048*4     =   131,072
  float4* boxes     = (float4*)(ws + 3011584);     // 16*2048*16    =   524,288
  uint32_t* counters= (uint32_t*)(ws + 3535872);   // 64
  ull* gmask        = (ull*)(ws + 3535936);        // 16*2048*32*8  = 8,388,608
  float* out = (float*)d_out;

  hipLaunchKernelGGL(k_score, dim3((TOTAL + 255) / 256), dim3(256), 0, stream, labels, bbox, keys);
  hipLaunchKernelGGL(k_batch, dim3(NB), dim3(1024), 0, stream, keys, selKeys, counters);
  hipLaunchKernelGGL(k_rank,  dim3(SELPAD / 256, NB), dim3(256), 0, stream, selKeys, counters, bbox, boxes, areas, selScore);
  hipLaunchKernelGGL(k_mask,  dim3(63, NB), dim3(256), 0, stream, boxes, areas, gmask);
  hipLaunchKernelGGL(k_scan,  dim3(NB), dim3(64), 0, stream, gmask, boxes, selScore, out);
}

// Round 21
// 111.847 us; speedup vs baseline: 1.3108x; 1.3108x over previous
//
#include <hip/hip_runtime.h>
#include <stdint.h>

// Match numpy's unfused mul/add rounding everywhere (no FMA contraction).
#pragma clang fp contract(off)

typedef unsigned long long ull;

// Problem constants (B=16, H=W=64, A=9, stride 16, img 1024x1024)
#define NB 16
#define NA 9
#define HW 4096
#define NANCH (NA*HW)         // 36864
#define TOTAL (NB*NANCH)      // 589824
#define TOPN 2000
#define PADN 2048             // box/area buffer stride
#define SELPAD 3072           // candidate buffer per batch
#define OUTN 300
#define HBITS 13
#define HBINS (1 << HBITS)    // 8192 LDS histogram bins
#define MROWS 2048            // mask row stride (rows 0..1999 written)
#define MW 32                 // ull words per mask row (2048 bits)
#define SG 8                  // strips per mask block (8*5=40 VGPR columns)

// exact: RN32(inter/u) > 0.7f  <=>  (double)inter >= MIDC*(double)u
// (HW-verified: absmax 0 in rounds 9-20.)
#define MIDC 0x1.666667p-1

// 9 base anchors (x1,y1,x2,y2), computed exactly per the numpy generator
__constant__ float c_ax1[9] = {-3.5f,-15.f,-38.f,  0.f, -8.f,-24.f,  2.5f, -3.f,-14.f};
__constant__ float c_ay1[9] = { 2.f,  -4.f,-16.f,  0.f, -8.f,-24.f, -3.f,-14.f,-36.f};
__constant__ float c_ax2[9] = {18.5f, 30.f, 53.f, 15.f, 23.f, 39.f, 12.5f, 18.f, 29.f};
__constant__ float c_ay2[9] = {13.f,  19.f, 31.f, 15.f, 23.f, 39.f, 18.f,  29.f, 51.f};

__device__ __forceinline__ void decode_box(int a, int x, int y,
    float d0, float d1, float d2, float d3,
    float& x1, float& y1, float& x2, float& y2) {
  float ax1 = c_ax1[a] + 16.f * (float)x;
  float ay1 = c_ay1[a] + 16.f * (float)y;
  float ax2 = c_ax2[a] + 16.f * (float)x;
  float ay2 = c_ay2[a] + 16.f * (float)y;
  float aw  = ax2 - ax1 + 1.f;
  float ah  = ay2 - ay1 + 1.f;
  float acx = ax1 + 0.5f * aw;
  float acy = ay1 + 0.5f * ah;
  float cx = d0 * aw + acx;
  float cy = d1 * ah + acy;
  float pw = expf(d2) * aw;
  float ph = expf(d3) * ah;
  x1 = cx - 0.5f * pw;
  y1 = cy - 0.5f * ph;
  x2 = cx + 0.5f * pw;
  y2 = cy + 0.5f * ph;
  x1 = fminf(fmaxf(x1, 0.f), 1023.f);
  y1 = fminf(fmaxf(y1, 0.f), 1023.f);
  x2 = fminf(fmaxf(x2, 0.f), 1023.f);
  y2 = fminf(fmaxf(y2, 0.f), 1023.f);
}

__device__ __forceinline__ uint32_t f2ord(float f) {
  uint32_t u = __float_as_uint(f);
  return (u & 0x80000000u) ? ~u : (u | 0x80000000u);
}
__device__ __forceinline__ float ord2f(uint32_t u) {
  return (u & 0x80000000u) ? __uint_as_float(u ^ 0x80000000u) : __uint_as_float(~u);
}

// Kernel 1: masked ordered score keys, 4 anchors/thread. Proven round 16.
__global__ void k_score(const float* __restrict__ labels, const float* __restrict__ bbox,
                        uint32_t* __restrict__ keys) {
  int t4 = blockIdx.x * 256 + threadIdx.x;     // grid 576 -> t4 < TOTAL/4
  int p4 = t4 & 1023;                          // float4 index within (b,a) plane
  int pos = p4 << 2;
  int ba = t4 >> 10;                           // b*9 + a  (0..143)
  int a = ba % 9, b = ba / 9;
  float4 sc  = ((const float4*)(labels + ((b * 18 + 2 * a + 1) << 12)))[p4];
  const float* dpb = bbox + ((b * 36 + 4 * a) << 12);
  float4 d0v = ((const float4*)(dpb        ))[p4];
  float4 d1v = ((const float4*)(dpb +  4096))[p4];
  float4 d2v = ((const float4*)(dpb +  8192))[p4];
  float4 d3v = ((const float4*)(dpb + 12288))[p4];
  int y = pos >> 6, x0 = pos & 63;             // pos%4==0 -> never crosses row
  float scA[4] = { sc.x,  sc.y,  sc.z,  sc.w  };
  float d0A[4] = { d0v.x, d0v.y, d0v.z, d0v.w };
  float d1A[4] = { d1v.x, d1v.y, d1v.z, d1v.w };
  float d2A[4] = { d2v.x, d2v.y, d2v.z, d2v.w };
  float d3A[4] = { d3v.x, d3v.y, d3v.z, d3v.w };
  uint32_t kout[4];
#pragma unroll
  for (int k = 0; k < 4; ++k) {
    float x1, y1, x2, y2;
    decode_box(a, x0 + k, y, d0A[k], d1A[k], d2A[k], d3A[k], x1, y1, x2, y2);
    bool keep = (x2 - x1 + 1.f >= 16.f) && (y2 - y1 + 1.f >= 16.f);
    kout[k] = f2ord(keep ? scA[k] : -INFINITY);
  }
  ((uint4*)(keys + b * NANCH + (a << 12) + pos))[0] =
      make_uint4(kout[0], kout[1], kout[2], kout[3]);
}

// Kernel 2: per-batch LDS histogram + suffix scan for top-2000 threshold bin
// + compaction. 16 blocks x 1024. Proven round 15.
__global__ __launch_bounds__(1024) void k_batch(const uint32_t* __restrict__ keys,
                                                ull* __restrict__ selKeys,
                                                uint32_t* __restrict__ counters) {
  int b = blockIdx.x, tid = threadIdx.x;
  int wave = tid >> 6, lane = tid & 63;
  __shared__ uint32_t hist[HBINS];         // 32 KB
  __shared__ uint32_t wtot[16];
  __shared__ uint32_t sh_T, sh_cnt;
  const uint32_t* kb = keys + b * NANCH;
  const uint4* kb4 = (const uint4*)kb;
#pragma unroll
  for (int k = 0; k < HBINS / 1024; ++k) hist[k * 1024 + tid] = 0u;
  if (tid == 0) { sh_T = 0u; sh_cnt = 0u; }
  __syncthreads();
  for (int i4 = tid; i4 < NANCH / 4; i4 += 1024) {
    uint4 v = kb4[i4];
    if (v.x & 0x80000000u) atomicAdd(&hist[v.x >> (32 - HBITS)], 1u);
    if (v.y & 0x80000000u) atomicAdd(&hist[v.y >> (32 - HBITS)], 1u);
    if (v.z & 0x80000000u) atomicAdd(&hist[v.z >> (32 - HBITS)], 1u);
    if (v.w & 0x80000000u) atomicAdd(&hist[v.w >> (32 - HBITS)], 1u);
  }
  __syncthreads();
  uint32_t c[8], suf[8];
#pragma unroll
  for (int k = 0; k < 8; ++k) c[k] = hist[tid * 8 + k];
  suf[7] = c[7];
#pragma unroll
  for (int k = 6; k >= 0; --k) suf[k] = c[k] + suf[k + 1];
  uint32_t total = suf[0];
  uint32_t wsuf = total;
#pragma unroll
  for (int off = 1; off < 64; off <<= 1) {
    uint32_t v = __shfl_down(wsuf, off);
    if (lane + off < 64) wsuf += v;
  }
  if (lane == 0) wtot[wave] = wsuf;
  __syncthreads();
  uint32_t wab = 0;
  for (int w = wave + 1; w < 16; ++w) wab += wtot[w];
  uint32_t ssum = wsuf + wab;          // keys in bins >= 8*tid
  uint32_t above_t = ssum - total;     // keys in bins >= 8*(tid+1)
  if (above_t < TOPN && ssum >= TOPN) {
    uint32_t T = (uint32_t)(tid * 8);
#pragma unroll
    for (int k = 7; k >= 0; --k) {
      uint32_t ab = above_t + ((k < 7) ? suf[k + 1] : 0u);
      if (ab < TOPN && ab + c[k] >= TOPN) T = (uint32_t)(tid * 8 + k);
    }
    sh_T = T;
  }
  __syncthreads();
  uint32_t T = sh_T;
  for (int i4 = tid; i4 < NANCH / 4; i4 += 1024) {
    uint4 v = kb4[i4];
    uint32_t vv[4] = { v.x, v.y, v.z, v.w };
#pragma unroll
    for (int cc = 0; cc < 4; ++cc) {
      uint32_t u = vv[cc];
      if ((u >> (32 - HBITS)) >= T) {
        uint32_t slot = atomicAdd(&sh_cnt, 1u);
        if (slot < SELPAD) {
          int i = i4 * 4 + cc;
          uint32_t canon = (uint32_t)((i & 4095) * 9 + (i >> 12));  // pos*9 + a
          selKeys[b * SELPAD + slot] = (((ull)(~u)) << 32) | canon;
        }
      }
    }
  }
  __syncthreads();
  if (tid == 0) counters[b] = (sh_cnt < SELPAD) ? sh_cnt : SELPAD;
}

// Kernel 3: rank-by-counting + decode + scatter. Proven round 15.
__global__ __launch_bounds__(256) void k_rank(const ull* __restrict__ selKeys,
                        const uint32_t* __restrict__ counters, const float* __restrict__ bbox,
                        float4* __restrict__ boxes, float* __restrict__ areas,
                        float* __restrict__ selScore) {
  int b = blockIdx.y;
  int i = blockIdx.x * 256 + threadIdx.x;
  int tid = threadIdx.x;
  uint32_t n = counters[b];
  const ull* sk = selKeys + b * SELPAD;
  ull ki = (i < (int)n) ? sk[i] : ~0ull;
  int rank = 0;
  __shared__ ull chunk[256];
  for (uint32_t base = 0; base < n; base += 256) {
    uint32_t j = base + (uint32_t)tid;
    chunk[tid] = (j < n) ? sk[j] : ~0ull;
    __syncthreads();
    int lim = (int)(n - base < 256u ? n - base : 256u);
    for (int t2 = 0; t2 < lim; ++t2) rank += (chunk[t2] < ki) ? 1 : 0;
    __syncthreads();
  }
  if (i < (int)n && rank < TOPN) {
    uint32_t idx = (uint32_t)ki;
    selScore[b * TOPN + rank] = ord2f(~((uint32_t)(ki >> 32)));
    int pos = (int)idx / 9, a = (int)idx - 9 * pos;
    int y = pos >> 6, x = pos & 63;
    const float* dp = bbox + ((b * 36 + 4 * a) << 12) + pos;
    float d0 = dp[0], d1 = dp[4096], d2 = dp[8192], d3 = dp[12288];
    float x1, y1, x2, y2;
    decode_box(a, x, y, d0, d1, d2, d3, x1, y1, x2, y2);
    boxes[b * PADN + rank] = make_float4(x1, y1, x2, y2);
    areas[b * PADN + rank] = (x2 - x1 + 1.f) * (y2 - y1 + 1.f);
  }
}

// Kernel 4: FULL suppression mask via register-resident column groups.
// Grid (63 row-blocks, 4 groups of SG=8 strips, 16 batches) x 256. Block owns
// 32 rows x 8 strips; column boxes in registers (loaded once); rows broadcast
// from LDS; one ballot per 64-bit word. Groups entirely below the diagonal
// (g*SG+SG-1 < smin) are skipped — the scan masks those unwritten words.
__global__ __launch_bounds__(256) void k_mask(const float4* __restrict__ boxes,
                                              const float* __restrict__ areas,
                                              ull* __restrict__ gmask) {
  int rb = blockIdx.x, g = blockIdx.y, b = blockIdx.z;
  int rbase = rb * 32;
  int smin = rbase >> 6;
  int s0 = g * SG;
  if (s0 + SG - 1 < smin) return;            // entirely below diagonal
  int tid = threadIdx.x, wv = tid >> 6, lane = tid & 63;
  __shared__ float4 sRow[32];
  __shared__ float  sAr[32];
  if (tid < 32) {
    sRow[tid] = boxes[b * PADN + rbase + tid];
    sAr[tid]  = areas[b * PADN + rbase + tid];
  }
  float4 bj[SG];
  float  ja[SG];
#pragma unroll
  for (int s = 0; s < SG; ++s) {
    int j = ((s0 + s) << 6) + lane;          // <= 2047, in-bounds
    bj[s] = boxes[b * PADN + j];
    ja[s] = areas[b * PADN + j];
  }
  __syncthreads();
  const double MD = MIDC;
  for (int r = wv; r < 32; r += 4) {
    int i = rbase + r;
    float4 bi = sRow[r];
    float  ia = sAr[r];
#pragma unroll
    for (int s = 0; s < SG; ++s) {
      int j = ((s0 + s) << 6) + lane;
      float iw = fminf(bi.z, bj[s].z) - fmaxf(bi.x, bj[s].x) + 1.f; iw = fmaxf(iw, 0.f);
      float ih = fminf(bi.w, bj[s].w) - fmaxf(bi.y, bj[s].y) + 1.f; ih = fmaxf(ih, 0.f);
      float inter = iw * ih;
      float uu = (ia + ja[s]) - inter;
      bool sup = (j < TOPN) && (j > i) && ((double)inter >= MD * (double)uu);
      ull mb = __ballot(sup);
      if (lane == 0 && i < TOPN) gmask[((size_t)b * MROWS + i) * MW + (s0 + s)] = mb;
    }
  }
}

// Kernel 5: fast serial greedy scan. Candidates processed in 32-aligned
// chunks (= one u32 bitmap word c): sw = shfl(supw, c) once per chunk; inside,
// the serial chain is only t=(sw>>ph)&1 -> sw |= diag & (t-1)  (~3 VALU ops).
// Full-row ORs into supw are off the critical path. Rows' own-word and
// diagonal-word double-buffered in registers (prefetch next chunk). Exact:
// bit i accumulates exactly the kept rows < i (prior chunks via shfl, current
// chunk via diag word, which holds row r's bits for columns in word c with
// j>r guard). Early exit at 300 kept. Rows >= TOPN forced suppressed.
__global__ __launch_bounds__(64) void k_scan(const ull* __restrict__ gmask,
                                             const float4* __restrict__ boxes,
                                             const float* __restrict__ selScore,
                                             float* __restrict__ out) {
  int b = blockIdx.x, lane = threadIdx.x;   // 64 threads = 1 wave
  const uint32_t* mrows = (const uint32_t*)(gmask + (size_t)b * MROWS * MW);
  __shared__ int kidx[OUTN];
  __shared__ int sh_cnt;
  uint32_t supw = 0u;                       // lane l owns u32 word l
  int cnt = 0;
  uint32_t mA[32], dA[32], mB[32], dB[32];
#pragma unroll
  for (int ph = 0; ph < 32; ++ph) {         // preload chunk 0
    mA[ph] = mrows[ph * 64 + lane];
    dA[ph] = mrows[ph * 64 + 0];
  }

#define PREFETCH(MARR, DARR, CN)                                             \
  {                                                                          \
    int cn_ = (CN) > 62 ? 62 : (CN);                                         \
    _Pragma("unroll")                                                        \
    for (int ph = 0; ph < 32; ++ph) {                                        \
      int r = cn_ * 32 + ph;                                                 \
      MARR[ph] = mrows[r * 64 + lane];                                       \
      DARR[ph] = mrows[r * 64 + cn_];                                        \
    }                                                                        \
  }

#define CHUNK(CC, MARR, DARR)                                                \
  {                                                                          \
    uint32_t sw = __shfl(supw, (CC));                                        \
    _Pragma("unroll")                                                        \
    for (int ph = 0; ph < 32; ++ph) {                                        \
      int i = (CC) * 32 + ph;                                                \
      uint32_t t = (sw >> ph) & 1u;                                          \
      if (i >= TOPN) t = 1u;                                                 \
      uint32_t keepm = t - 1u;              /* all-ones iff kept */          \
      uint32_t mm = (lane >= (uint32_t)((i >> 6) << 1)) ? MARR[ph] : 0u;     \
      supw |= mm & keepm;                                                    \
      sw   |= DARR[ph] & keepm;                                              \
      if (lane == 0 && t == 0u && cnt < OUTN) kidx[cnt] = i;                 \
      cnt += (int)(t ^ 1u);                                                  \
    }                                                                        \
  }

  for (int cc = 0; cc < 63; cc += 2) {
    PREFETCH(mB, dB, cc + 1);
    CHUNK(cc, mA, dA);
    if (cnt >= OUTN) break;
    PREFETCH(mA, dA, cc + 2);
    CHUNK(cc + 1, mB, dB);
    if (cnt >= OUTN) break;
  }
#undef CHUNK
#undef PREFETCH

  if (lane == 0) sh_cnt = (cnt < OUTN) ? cnt : OUTN;
  __syncthreads();
  int c = sh_cnt;
  float4* ob = (float4*)out;
  for (int s2 = lane; s2 < OUTN; s2 += 64) {
    float4 bx = make_float4(0.f, 0.f, 0.f, 0.f);
    float sc = 0.f;
    if (s2 < c) {
      int i = kidx[s2];
      bx = boxes[b * PADN + i];
      sc = selScore[b * TOPN + i];
    }
    ob[b * OUTN + s2] = bx;
    out[NB * OUTN * 4 + b * OUTN + s2] = sc;
  }
}

extern "C" void kernel_launch(void* const* d_in, const int* in_sizes, int n_in,
                              void* d_out, int out_size, void* d_ws, size_t ws_size,
                              hipStream_t stream) {
  const float* labels = (const float*)d_in[0];  // (16, 18, 64, 64)
  const float* bbox   = (const float*)d_in[1];  // (16, 36, 64, 64)
  char* ws = (char*)d_ws;
  // workspace layout (bytes):
  uint32_t* keys    = (uint32_t*)(ws + 0);         // 589824*4      = 2,359,296
  ull* selKeys      = (ull*)(ws + 2359296);        // 16*3072*8     =   393,216
  float* selScore   = (float*)(ws + 2752512);      // 16*2000*4     =   128,000
  float* areas      = (float*)(ws + 2880512);      // 16*2048*4     =   131,072
  float4* boxes     = (float4*)(ws + 3011584);     // 16*2048*16    =   524,288
  uint32_t* counters= (uint32_t*)(ws + 3535872);   // 64
  ull* gmask        = (ull*)(ws + 3535936);        // 16*2048*32*8  = 8,388,608
  float* out = (float*)d_out;

  hipLaunchKernelGGL(k_score, dim3(TOTAL / 4 / 256), dim3(256), 0, stream, labels, bbox, keys);
  hipLaunchKernelGGL(k_batch, dim3(NB), dim3(1024), 0, stream, keys, selKeys, counters);
  hipLaunchKernelGGL(k_rank,  dim3(SELPAD / 256, NB), dim3(256), 0, stream, selKeys, counters, bbox, boxes, areas, selScore);
  hipLaunchKernelGGL(k_mask,  dim3(63, 4, NB), dim3(256), 0, stream, boxes, areas, gmask);
  hipLaunchKernelGGL(k_scan,  dim3(NB), dim3(64), 0, stream, gmask, boxes, selScore, out);
}

// Round 22
// 89.934 us; speedup vs baseline: 1.6302x; 1.2437x over previous
//
#include <hip/hip_runtime.h>
#include <stdint.h>

// Match numpy's unfused mul/add rounding everywhere (no FMA contraction).
#pragma clang fp contract(off)

typedef unsigned long long ull;

// Problem constants (B=16, H=W=64, A=9, stride 16, img 1024x1024)
#define NB 16
#define NA 9
#define HW 4096
#define NANCH (NA*HW)         // 36864
#define TOTAL (NB*NANCH)      // 589824
#define TOPN 2000
#define PADN 2048             // box/area buffer stride
#define SELPAD 3072           // candidate buffer per batch
#define OUTN 300
#define HBITS 13
#define HBINS (1 << HBITS)    // 8192 LDS histogram bins
#define MNMS 384              // mask extent (r15-proven best combination)
#define MSTRIPS (MNMS/64)     // 6 ull words per row
#define MPITCH 8              // row pitch in ull words (64B-aligned rows)
#define GD2 16                // scan prefetch depth

// exact: RN32(inter/u) > 0.7f  <=>  (double)inter >= MIDC*(double)u
// (HW-verified: absmax 0 in rounds 9-21.)
#define MIDC 0x1.666667p-1

// 9 base anchors (x1,y1,x2,y2), computed exactly per the numpy generator
__constant__ float c_ax1[9] = {-3.5f,-15.f,-38.f,  0.f, -8.f,-24.f,  2.5f, -3.f,-14.f};
__constant__ float c_ay1[9] = { 2.f,  -4.f,-16.f,  0.f, -8.f,-24.f, -3.f,-14.f,-36.f};
__constant__ float c_ax2[9] = {18.5f, 30.f, 53.f, 15.f, 23.f, 39.f, 12.5f, 18.f, 29.f};
__constant__ float c_ay2[9] = {13.f,  19.f, 31.f, 15.f, 23.f, 39.f, 18.f,  29.f, 51.f};

__device__ __forceinline__ void decode_box(int a, int x, int y,
    float d0, float d1, float d2, float d3,
    float& x1, float& y1, float& x2, float& y2) {
  float ax1 = c_ax1[a] + 16.f * (float)x;
  float ay1 = c_ay1[a] + 16.f * (float)y;
  float ax2 = c_ax2[a] + 16.f * (float)x;
  float ay2 = c_ay2[a] + 16.f * (float)y;
  float aw  = ax2 - ax1 + 1.f;
  float ah  = ay2 - ay1 + 1.f;
  float acx = ax1 + 0.5f * aw;
  float acy = ay1 + 0.5f * ah;
  float cx = d0 * aw + acx;
  float cy = d1 * ah + acy;
  float pw = expf(d2) * aw;
  float ph = expf(d3) * ah;
  x1 = cx - 0.5f * pw;
  y1 = cy - 0.5f * ph;
  x2 = cx + 0.5f * pw;
  y2 = cy + 0.5f * ph;
  x1 = fminf(fmaxf(x1, 0.f), 1023.f);
  y1 = fminf(fmaxf(y1, 0.f), 1023.f);
  x2 = fminf(fmaxf(x2, 0.f), 1023.f);
  y2 = fminf(fmaxf(y2, 0.f), 1023.f);
}

__device__ __forceinline__ uint32_t f2ord(float f) {
  uint32_t u = __float_as_uint(f);
  return (u & 0x80000000u) ? ~u : (u | 0x80000000u);
}
__device__ __forceinline__ float ord2f(uint32_t u) {
  return (u & 0x80000000u) ? __uint_as_float(u ^ 0x80000000u) : __uint_as_float(~u);
}

// Kernel 1: masked ordered score keys, 4 anchors/thread (float4 loads, uint4
// store, [b][a][pos] layout). Proven rounds 16/17/19.
__global__ void k_score(const float* __restrict__ labels, const float* __restrict__ bbox,
                        uint32_t* __restrict__ keys) {
  int t4 = blockIdx.x * 256 + threadIdx.x;     // grid 576 -> t4 < TOTAL/4
  int p4 = t4 & 1023;                          // float4 index within (b,a) plane
  int pos = p4 << 2;
  int ba = t4 >> 10;                           // b*9 + a  (0..143)
  int a = ba % 9, b = ba / 9;
  float4 sc  = ((const float4*)(labels + ((b * 18 + 2 * a + 1) << 12)))[p4];
  const float* dpb = bbox + ((b * 36 + 4 * a) << 12);
  float4 d0v = ((const float4*)(dpb        ))[p4];
  float4 d1v = ((const float4*)(dpb +  4096))[p4];
  float4 d2v = ((const float4*)(dpb +  8192))[p4];
  float4 d3v = ((const float4*)(dpb + 12288))[p4];
  int y = pos >> 6, x0 = pos & 63;             // pos%4==0 -> never crosses row
  float scA[4] = { sc.x,  sc.y,  sc.z,  sc.w  };
  float d0A[4] = { d0v.x, d0v.y, d0v.z, d0v.w };
  float d1A[4] = { d1v.x, d1v.y, d1v.z, d1v.w };
  float d2A[4] = { d2v.x, d2v.y, d2v.z, d2v.w };
  float d3A[4] = { d3v.x, d3v.y, d3v.z, d3v.w };
  uint32_t kout[4];
#pragma unroll
  for (int k = 0; k < 4; ++k) {
    float x1, y1, x2, y2;
    decode_box(a, x0 + k, y, d0A[k], d1A[k], d2A[k], d3A[k], x1, y1, x2, y2);
    bool keep = (x2 - x1 + 1.f >= 16.f) && (y2 - y1 + 1.f >= 16.f);
    kout[k] = f2ord(keep ? scA[k] : -INFINITY);
  }
  ((uint4*)(keys + b * NANCH + (a << 12) + pos))[0] =
      make_uint4(kout[0], kout[1], kout[2], kout[3]);
}

// Kernel 2: per-batch LDS histogram + suffix scan for top-2000 threshold bin
// + compaction. 16 blocks x 1024. Proven round 15.
__global__ __launch_bounds__(1024) void k_batch(const uint32_t* __restrict__ keys,
                                                ull* __restrict__ selKeys,
                                                uint32_t* __restrict__ counters) {
  int b = blockIdx.x, tid = threadIdx.x;
  int wave = tid >> 6, lane = tid & 63;
  __shared__ uint32_t hist[HBINS];         // 32 KB
  __shared__ uint32_t wtot[16];
  __shared__ uint32_t sh_T, sh_cnt;
  const uint32_t* kb = keys + b * NANCH;
  const uint4* kb4 = (const uint4*)kb;
#pragma unroll
  for (int k = 0; k < HBINS / 1024; ++k) hist[k * 1024 + tid] = 0u;
  if (tid == 0) { sh_T = 0u; sh_cnt = 0u; }
  __syncthreads();
  for (int i4 = tid; i4 < NANCH / 4; i4 += 1024) {
    uint4 v = kb4[i4];
    if (v.x & 0x80000000u) atomicAdd(&hist[v.x >> (32 - HBITS)], 1u);
    if (v.y & 0x80000000u) atomicAdd(&hist[v.y >> (32 - HBITS)], 1u);
    if (v.z & 0x80000000u) atomicAdd(&hist[v.z >> (32 - HBITS)], 1u);
    if (v.w & 0x80000000u) atomicAdd(&hist[v.w >> (32 - HBITS)], 1u);
  }
  __syncthreads();
  uint32_t c[8], suf[8];
#pragma unroll
  for (int k = 0; k < 8; ++k) c[k] = hist[tid * 8 + k];
  suf[7] = c[7];
#pragma unroll
  for (int k = 6; k >= 0; --k) suf[k] = c[k] + suf[k + 1];
  uint32_t total = suf[0];
  uint32_t wsuf = total;
#pragma unroll
  for (int off = 1; off < 64; off <<= 1) {
    uint32_t v = __shfl_down(wsuf, off);
    if (lane + off < 64) wsuf += v;
  }
  if (lane == 0) wtot[wave] = wsuf;
  __syncthreads();
  uint32_t wab = 0;
  for (int w = wave + 1; w < 16; ++w) wab += wtot[w];
  uint32_t ssum = wsuf + wab;          // keys in bins >= 8*tid
  uint32_t above_t = ssum - total;     // keys in bins >= 8*(tid+1)
  if (above_t < TOPN && ssum >= TOPN) {
    uint32_t T = (uint32_t)(tid * 8);
#pragma unroll
    for (int k = 7; k >= 0; --k) {
      uint32_t ab = above_t + ((k < 7) ? suf[k + 1] : 0u);
      if (ab < TOPN && ab + c[k] >= TOPN) T = (uint32_t)(tid * 8 + k);
    }
    sh_T = T;
  }
  __syncthreads();
  uint32_t T = sh_T;
  for (int i4 = tid; i4 < NANCH / 4; i4 += 1024) {
    uint4 v = kb4[i4];
    uint32_t vv[4] = { v.x, v.y, v.z, v.w };
#pragma unroll
    for (int cc = 0; cc < 4; ++cc) {
      uint32_t u = vv[cc];
      if ((u >> (32 - HBITS)) >= T) {
        uint32_t slot = atomicAdd(&sh_cnt, 1u);
        if (slot < SELPAD) {
          int i = i4 * 4 + cc;
          uint32_t canon = (uint32_t)((i & 4095) * 9 + (i >> 12));  // pos*9 + a
          selKeys[b * SELPAD + slot] = (((ull)(~u)) << 32) | canon;
        }
      }
    }
  }
  __syncthreads();
  if (tid == 0) counters[b] = (sh_cnt < SELPAD) ? sh_cnt : SELPAD;
}

// Kernel 3: rank-by-counting + decode + scatter. Proven round 15.
__global__ __launch_bounds__(256) void k_rank(const ull* __restrict__ selKeys,
                        const uint32_t* __restrict__ counters, const float* __restrict__ bbox,
                        float4* __restrict__ boxes, float* __restrict__ areas,
                        float* __restrict__ selScore) {
  int b = blockIdx.y;
  int i = blockIdx.x * 256 + threadIdx.x;
  int tid = threadIdx.x;
  uint32_t n = counters[b];
  const ull* sk = selKeys + b * SELPAD;
  ull ki = (i < (int)n) ? sk[i] : ~0ull;
  int rank = 0;
  __shared__ ull chunk[256];
  for (uint32_t base = 0; base < n; base += 256) {
    uint32_t j = base + (uint32_t)tid;
    chunk[tid] = (j < n) ? sk[j] : ~0ull;
    __syncthreads();
    int lim = (int)(n - base < 256u ? n - base : 256u);
    for (int t2 = 0; t2 < lim; ++t2) rank += (chunk[t2] < ki) ? 1 : 0;
    __syncthreads();
  }
  if (i < (int)n && rank < TOPN) {
    uint32_t idx = (uint32_t)ki;
    selScore[b * TOPN + rank] = ord2f(~((uint32_t)(ki >> 32)));
    int pos = (int)idx / 9, a = (int)idx - 9 * pos;
    int y = pos >> 6, x = pos & 63;
    const float* dp = bbox + ((b * 36 + 4 * a) << 12) + pos;
    float d0 = dp[0], d1 = dp[4096], d2 = dp[8192], d3 = dp[12288];
    float x1, y1, x2, y2;
    decode_box(a, x, y, d0, d1, d2, d3, x1, y1, x2, y2);
    boxes[b * PADN + rank] = make_float4(x1, y1, x2, y2);
    areas[b * PADN + rank] = (x2 - x1 + 1.f) * (y2 - y1 + 1.f);
  }
}

// Kernel 4: suppression mask build, 192 balanced blocks: grid (12, 16) x 256.
// Block owns 32 consecutive rows (shares smin = rbase>>6) and writes words
// s in [smin, 6). Lane owns column (s<<6)+lane (box in registers); one
// __ballot builds each 64-bit word. Proven round 15.
__global__ __launch_bounds__(256) void k_mask(const float4* __restrict__ boxes,
                                              const float* __restrict__ areas,
                                              ull* __restrict__ gmask) {
  int rb = blockIdx.x, b = blockIdx.y;
  int tid = threadIdx.x, wv = tid >> 6, lane = tid & 63;
  int rbase = rb * 32;
  int smin = rbase >> 6;
  __shared__ float4 sRow[32];
  __shared__ float  sAr[32];
  if (tid < 32) {
    sRow[tid] = boxes[b * PADN + rbase + tid];
    sAr[tid]  = areas[b * PADN + rbase + tid];
  }
  float4 bj[MSTRIPS];
  float  ja[MSTRIPS];
#pragma unroll
  for (int s = 0; s < MSTRIPS; ++s) {
    if (s >= smin) {
      bj[s] = boxes[b * PADN + (s << 6) + lane];
      ja[s] = areas[b * PADN + (s << 6) + lane];
    }
  }
  __syncthreads();
  const double MD = MIDC;
  for (int r = wv; r < 32; r += 4) {
    int i = rbase + r;
    float4 bi = sRow[r];
    float  ia = sAr[r];
#pragma unroll
    for (int s = 0; s < MSTRIPS; ++s) {
      if (s < smin) continue;
      int j = (s << 6) + lane;
      float iw = fminf(bi.z, bj[s].z) - fmaxf(bi.x, bj[s].x) + 1.f; iw = fmaxf(iw, 0.f);
      float ih = fminf(bi.w, bj[s].w) - fmaxf(bi.y, bj[s].y) + 1.f; ih = fmaxf(ih, 0.f);
      float inter = iw * ih;
      float uu = (ia + ja[s]) - inter;
      bool sup = (j > i) && ((double)inter >= MD * (double)uu);
      ull mb = __ballot(sup);
      if (lane == 0) gmask[((size_t)b * MNMS + i) * MPITCH + s] = mb;
    }
  }
}

// Kernel 5: single-wave greedy scan per batch over the global mask matrix
// (64B-aligned rows, L2-resident), GD2-deep register prefetch, ballot bit
// test, exact early exit at 300 kept. Exact fallback (vs kept list) for
// candidates >= MNMS. Proven round 15 (90.4 us total).
__global__ __launch_bounds__(64) void k_scan(const ull* __restrict__ gmask,
                                             const float4* __restrict__ boxes,
                                             const float* __restrict__ areas,
                                             const float* __restrict__ selScore,
                                             float* __restrict__ out) {
  int b = blockIdx.x, lane = threadIdx.x;   // 64 threads = 1 wave
  const ull* mb = gmask + (size_t)b * MNMS * MPITCH;
  int l8 = lane & 7;
  __shared__ int kidx[OUTN];
  __shared__ int sh_cnt;
  const double MD = MIDC;
  ull supw = 0ull;
  int cnt = 0;
  ull pf[GD2];
#pragma unroll
  for (int ph = 0; ph < GD2; ++ph) pf[ph] = mb[ph * MPITCH + l8];
  for (int base = 0; base < MNMS && cnt < OUTN; base += GD2) {
#pragma unroll
    for (int ph = 0; ph < GD2; ++ph) {
      int i = base + ph;
      ull bal = __ballot(((supw >> (i & 63)) & 1ull) != 0ull);
      if (!((bal >> (i >> 6)) & 1ull)) {       // uniform (lane i>>6 owns word)
        ull mm = (l8 >= (i >> 6) && l8 < MSTRIPS) ? pf[ph] : 0ull;
        supw |= mm;
        if (lane == 0 && cnt < OUTN) kidx[cnt] = i;
        cnt++;
      }
      int nx = i + GD2; if (nx > MNMS - 1) nx = MNMS - 1;
      pf[ph] = mb[nx * MPITCH + l8];           // prefetch
    }
  }
  // exact fallback: candidates beyond the mask matrix
  for (int i = MNMS; i < TOPN && cnt < OUTN; ++i) {
    float4 bi = boxes[b * PADN + i];
    float ia = areas[b * PADN + i];
    bool sup = false;
    for (int cb = 0; cb < cnt; cb += 64) {
      int k = cb + lane;
      if (k < cnt) {
        int kj = kidx[k];
        float4 bk = boxes[b * PADN + kj];
        float ka = areas[b * PADN + kj];
        float iw = fminf(bi.z, bk.z) - fmaxf(bi.x, bk.x) + 1.f; iw = fmaxf(iw, 0.f);
        float ih = fminf(bi.w, bk.w) - fmaxf(bi.y, bk.y) + 1.f; ih = fmaxf(ih, 0.f);
        float inter = iw * ih;
        float uu = (ia + ka) - inter;
        sup = sup || ((double)inter >= MD * (double)uu);
      }
    }
    if (!__any(sup)) {
      if (lane == 0) kidx[cnt] = i;
      cnt++;
    }
  }
  if (lane == 0) sh_cnt = (cnt < OUTN) ? cnt : OUTN;
  __syncthreads();
  int c = sh_cnt;
  float4* ob = (float4*)out;
  for (int s2 = lane; s2 < OUTN; s2 += 64) {
    float4 bx = make_float4(0.f, 0.f, 0.f, 0.f);
    float sc = 0.f;
    if (s2 < c) {
      int i = kidx[s2];
      bx = boxes[b * PADN + i];
      sc = selScore[b * TOPN + i];
    }
    ob[b * OUTN + s2] = bx;
    out[NB * OUTN * 4 + b * OUTN + s2] = sc;
  }
}

extern "C" void kernel_launch(void* const* d_in, const int* in_sizes, int n_in,
                              void* d_out, int out_size, void* d_ws, size_t ws_size,
                              hipStream_t stream) {
  const float* labels = (const float*)d_in[0];  // (16, 18, 64, 64)
  const float* bbox   = (const float*)d_in[1];  // (16, 36, 64, 64)
  char* ws = (char*)d_ws;
  // workspace layout (bytes):
  uint32_t* keys    = (uint32_t*)(ws + 0);         // 589824*4    = 2,359,296
  ull* selKeys      = (ull*)(ws + 2359296);        // 16*3072*8   =   393,216
  float* selScore   = (float*)(ws + 2752512);      // 16*2000*4   =   128,000
  float* areas      = (float*)(ws + 2880512);      // 16*2048*4   =   131,072
  float4* boxes     = (float4*)(ws + 3011584);     // 16*2048*16  =   524,288
  uint32_t* counters= (uint32_t*)(ws + 3535872);   // 64
  ull* gmask        = (ull*)(ws + 3535936);        // 16*384*8*8  =   393,216
  float* out = (float*)d_out;

  hipLaunchKernelGGL(k_score, dim3(TOTAL / 4 / 256), dim3(256), 0, stream, labels, bbox, keys);
  hipLaunchKernelGGL(k_batch, dim3(NB), dim3(1024), 0, stream, keys, selKeys, counters);
  hipLaunchKernelGGL(k_rank,  dim3(SELPAD / 256, NB), dim3(256), 0, stream, selKeys, counters, bbox, boxes, areas, selScore);
  hipLaunchKernelGGL(k_mask,  dim3(MNMS / 32, NB), dim3(256), 0, stream, boxes, areas, gmask);
  hipLaunchKernelGGL(k_scan,  dim3(NB), dim3(64), 0, stream, gmask, boxes, areas, selScore, out);
}